// Round 6
// baseline (447.674 us; speedup 1.0000x reference)
//
#include <hip/hip_runtime.h>

// WaveCell round-12: ROLLED step loop (I-cache theory).
// Invariant since round 6: ~19us per 16-step phase regardless of VALU cuts,
// store drains, or handshake design; VALUBusy 12%. The one constant: a
// #pragma unroll 16 step body (~15-20KB of straight-line code) re-streamed
// through L1I from L2 once per phase by every CU. Fix: roll the loop so the
// body (<1KB) stays I-cache resident. Enablers: xs[] moved to LDS (runtime
// index on a register array would spill to scratch); alive/til/step guards
// become uniform runtime branches (execz still skips dead waves).
// Carried from round-11: coop launch + fence-free neighbor-flag pipeline
// (sc0 sc1 write-through stores -> no wbl2/inv needed), fused 7-op cell,
// trapezoid row-gating, lgkm-only step barriers, pipelined output stores,
// masked lg==7 shuffle, hoisted coefficients. Fallback: 16 classic launches.

#define NXg 192
#define NYg 192
#define BATCH 4
#define TSTEPS 256
#define CELLS (NXg * NYg)

#define TS 24                   // output tile side
#define KSTEP 16                // time steps per phase
#define NPHASE (TSTEPS / KSTEP) // 16
#define EXT 56                  // TS + 2*KSTEP
#define LROWS (EXT + 2)         // rows 1..56 used; 0/57 never read
#define LPITCH 68               // dwords/row: 4 pad | 56 data | 8 pad
#define LSZ (LROWS * LPITCH)
#define NTHREADS 448            // 56 rows x 8 lanes/row = 7 waves

#define SRC_X 96
#define SRC_Y 32

typedef float __attribute__((ext_vector_type(4))) f32x4;

// Device-coherent 16B store: write-through past the XCD L2 to LLC.
__device__ __forceinline__ void store_f4_dc(float* p, float4 v) {
  f32x4 w;
  w.x = v.x; w.y = v.y; w.z = v.z; w.w = v.w;
  asm volatile("global_store_dwordx4 %0, %1, off sc0 sc1"
               :
               : "v"(p), "v"(w)
               : "memory");
}

__global__ __launch_bounds__(NTHREADS) void wave_kernel(
    const float* __restrict__ cgp, const float* __restrict__ bgp,
    const float* __restrict__ x, float* __restrict__ out,
    unsigned int* __restrict__ flags, int p0, int p1) {
  __shared__ float buf0[LSZ];
  __shared__ float buf1[LSZ];
  __shared__ float xsL[KSTEP];

  const int tid = threadIdx.x;
  const int lr = tid >> 3;      // local row 0..55
  const int lg = tid & 7;       // 8-wide group in row; lg==7 is the zero lane
  const int bcol = blockIdx.x;  // 0..7
  const int brow = blockIdx.y;  // 0..7
  const int bb = blockIdx.z;    // 0..3
  const int r0 = brow * TS - KSTEP;
  const int c0 = bcol * TS - KSTEP;
  const int obase = bb * TSTEPS * CELLS;
  const float inv_h2 = (float)(1.0 / (2.0 * 1.01 * 1.01 * 1.0e-3 * 1.0e-3));

  const int gr = r0 + lr;
  const int gc = c0 + 8 * lg;  // multiple of 8; never straddles domain edge
  const bool id = (lg < 7) && (gr >= 0) && (gr < NXg) && (gc >= 0) && (gc < NYg);
  const bool til = (lr >= KSTEP) && (lr < KSTEP + TS) && (lg >= 2) && (lg < 5);
  const bool hs = (SRC_X >= r0) && (SRC_X < r0 + EXT) &&
                  (SRC_Y >= c0) && (SRC_Y < c0 + EXT);
  const int gofs = id ? (gr * NYg + gc) : 0;

  // Pipeline handshake identity: own flag slot + (for tid<8) one neighbor.
  const int bid = (bb * 8 + brow) * 8 + bcol;
  int nbr_id = -1;
  if (tid < 8) {
    const int idx = (tid < 4) ? tid : tid + 1;  // skip center of 3x3
    const int nr = brow + idx / 3 - 1;
    const int nc = bcol + idx % 3 - 1;
    if (nr >= 0 && nr < 8 && nc >= 0 && nc < 8)
      nbr_id = (bb * 8 + nr) * 8 + nc;
  }

  const float4 z4 = make_float4(0.f, 0.f, 0.f, 0.f);

  // ---- Loop-invariant: c/b loads + fused coefficients + source mask. ----
  // val = Dc*yc - Ey*yp + G*(sum4 - 4*yc) [+ sm*xt]
  // !id lanes keep Dc=Ey=G=0 -> val identically 0 (zero padding / zero lane).
  float4 Dc0 = z4, Dc1 = z4, Ey0 = z4, Ey1 = z4, G0 = z4, G1 = z4;
  float4 sm0 = z4, sm1 = z4;
  if (id) {
    float4 cv0 = *(const float4*)(cgp + gofs);
    float4 cv1 = *(const float4*)(cgp + gofs + 4);
    float4 bv0 = *(const float4*)(bgp + gofs);
    float4 bv1 = *(const float4*)(bgp + gofs + 4);
    float ai;
    ai = 1.0f / (1.0e6f + 500.0f * bv0.x);
    Dc0.x = 2.0e6f * ai; Ey0.x = (1.0e6f - 500.0f * bv0.x) * ai;
    G0.x = (cv0.x * cv0.x) * inv_h2 * ai;
    ai = 1.0f / (1.0e6f + 500.0f * bv0.y);
    Dc0.y = 2.0e6f * ai; Ey0.y = (1.0e6f - 500.0f * bv0.y) * ai;
    G0.y = (cv0.y * cv0.y) * inv_h2 * ai;
    ai = 1.0f / (1.0e6f + 500.0f * bv0.z);
    Dc0.z = 2.0e6f * ai; Ey0.z = (1.0e6f - 500.0f * bv0.z) * ai;
    G0.z = (cv0.z * cv0.z) * inv_h2 * ai;
    ai = 1.0f / (1.0e6f + 500.0f * bv0.w);
    Dc0.w = 2.0e6f * ai; Ey0.w = (1.0e6f - 500.0f * bv0.w) * ai;
    G0.w = (cv0.w * cv0.w) * inv_h2 * ai;
    ai = 1.0f / (1.0e6f + 500.0f * bv1.x);
    Dc1.x = 2.0e6f * ai; Ey1.x = (1.0e6f - 500.0f * bv1.x) * ai;
    G1.x = (cv1.x * cv1.x) * inv_h2 * ai;
    ai = 1.0f / (1.0e6f + 500.0f * bv1.y);
    Dc1.y = 2.0e6f * ai; Ey1.y = (1.0e6f - 500.0f * bv1.y) * ai;
    G1.y = (cv1.y * cv1.y) * inv_h2 * ai;
    ai = 1.0f / (1.0e6f + 500.0f * bv1.z);
    Dc1.z = 2.0e6f * ai; Ey1.z = (1.0e6f - 500.0f * bv1.z) * ai;
    G1.z = (cv1.z * cv1.z) * inv_h2 * ai;
    ai = 1.0f / (1.0e6f + 500.0f * bv1.w);
    Dc1.w = 2.0e6f * ai; Ey1.w = (1.0e6f - 500.0f * bv1.w) * ai;
    G1.w = (cv1.w * cv1.w) * inv_h2 * ai;
    if (gr == SRC_X) {
      sm0.x = (gc + 0 == SRC_Y) ? 1.0f : 0.0f;
      sm0.y = (gc + 1 == SRC_Y) ? 1.0f : 0.0f;
      sm0.z = (gc + 2 == SRC_Y) ? 1.0f : 0.0f;
      sm0.w = (gc + 3 == SRC_Y) ? 1.0f : 0.0f;
      sm1.x = (gc + 4 == SRC_Y) ? 1.0f : 0.0f;
      sm1.y = (gc + 5 == SRC_Y) ? 1.0f : 0.0f;
      sm1.z = (gc + 6 == SRC_Y) ? 1.0f : 0.0f;
      sm1.w = (gc + 7 == SRC_Y) ? 1.0f : 0.0f;
    }
  }

  const int lo = (lr + 1) * LPITCH + 4 + 8 * lg;

#define CELL(dst, up_, dn_, lf_, rt_, D_, E_, Gc_, y_, p_)              \
  {                                                                     \
    float s_ = fmaf(-4.0f, y_, (up_ + dn_) + (lf_ + rt_));              \
    dst = fmaf(Gc_, s_, fmaf(-E_, p_, D_ * y_));                        \
  }

  for (int p = p0; p < p1; ++p) {
    const int t0 = p * KSTEP;

    if (p > p0) {
      // ---- Acquire: relaxed spin on neighbor flags; NO cache invalidate.
      // (Safe: this phase's loads hit addresses never previously cached by
      // this block, and the writers' stores were device-coherent sc0 sc1.)
      if (tid < 8 && nbr_id >= 0) {
        while (__hip_atomic_load(&flags[nbr_id], __ATOMIC_RELAXED,
                                 __HIP_MEMORY_SCOPE_AGENT) < (unsigned)p)
          __builtin_amdgcn_s_sleep(2);
      }
      __syncthreads();  // also a compiler memory barrier
    }

    // ---- Per-phase state reload (halo-extended region, 2 time slices). ----
    float4 yc0 = z4, yc1 = z4, yp0 = z4, yp1 = z4;
    if (id && t0 > 0) {
      yc0 = *(const float4*)(out + obase + (t0 - 1) * CELLS + gofs);
      yc1 = *(const float4*)(out + obase + (t0 - 1) * CELLS + gofs + 4);
      yp0 = *(const float4*)(out + obase + (t0 - 2) * CELLS + gofs);
      yp1 = *(const float4*)(out + obase + (t0 - 2) * CELLS + gofs + 4);
    }
    // Source series for this phase -> LDS (broadcast-read each step; a
    // register array would be runtime-indexed in the rolled loop = scratch).
    if (tid < 4) {
      float4 a = ((const float4*)(x + bb * TSTEPS + t0))[tid];
      *(float4*)&xsL[4 * tid] = a;
    }

    // Scatter y(t-1) into buf0 rows 1..56 (guard rows never read).
    *(float4*)&buf0[lo] = yc0;
    *(float4*)&buf0[lo + 4] = yc1;
    asm volatile("s_waitcnt lgkmcnt(0)\n\ts_barrier" ::: "memory");

    float* ping = buf0;
    float* pong = buf1;

    float4 pv0 = z4, pv1 = z4;
    float* pop = out;  // dummy; only used when j>0

    // ROLLED: body stays I-cache resident; j is a uniform runtime value.
#pragma clang loop unroll(disable)
    for (int j = 0; j < KSTEP; ++j) {
      float* op = out + obase + (t0 + j) * CELLS;

      // Store PREVIOUS step's output (device-coherent, write-through);
      // never drained inside the loop, drained at the phase-end barrier.
      if (j > 0 && til) {
        store_f4_dc(pop + gofs, pv0);
        store_f4_dc(pop + gofs + 4, pv1);
      }

      // Trapezoid gating: step j only needs rows [j+1, 54-j]; dead waves
      // skip via execz (runtime-computed exec mask, uniform per row).
      const bool alive = (lr >= j + 1) && (lr <= 54 - j);
      if (alive) {
        const float xt = xsL[j];  // LDS broadcast (same addr, no conflict)

        float lqw = __shfl_up(yc1.w, 1);
        lqw = (lg == 0) ? 0.0f : lqw;       // row's left edge neighbor is 0
        float rqx = __shfl_down(yc0.x, 1);  // lg==6 pulls zero lane -> 0
        rqx = (lg == 7) ? 0.0f : rqx;       // source lane may be exec-masked

        float4 up0 = *(float4*)&ping[lo - LPITCH];
        float4 up1 = *(float4*)&ping[lo - LPITCH + 4];
        float4 dn0 = *(float4*)&ping[lo + LPITCH];
        float4 dn1 = *(float4*)&ping[lo + LPITCH + 4];

        float4 val0, val1;
        CELL(val0.x, up0.x, dn0.x, lqw,    yc0.y, Dc0.x, Ey0.x, G0.x, yc0.x, yp0.x);
        CELL(val0.y, up0.y, dn0.y, yc0.x,  yc0.z, Dc0.y, Ey0.y, G0.y, yc0.y, yp0.y);
        CELL(val0.z, up0.z, dn0.z, yc0.y,  yc0.w, Dc0.z, Ey0.z, G0.z, yc0.z, yp0.z);
        CELL(val0.w, up0.w, dn0.w, yc0.z,  yc1.x, Dc0.w, Ey0.w, G0.w, yc0.w, yp0.w);
        CELL(val1.x, up1.x, dn1.x, yc0.w,  yc1.y, Dc1.x, Ey1.x, G1.x, yc1.x, yp1.x);
        CELL(val1.y, up1.y, dn1.y, yc1.x,  yc1.z, Dc1.y, Ey1.y, G1.y, yc1.y, yp1.y);
        CELL(val1.z, up1.z, dn1.z, yc1.y,  yc1.w, Dc1.z, Ey1.z, G1.z, yc1.z, yp1.z);
        CELL(val1.w, up1.w, dn1.w, yc1.z,  rqx,   Dc1.w, Ey1.w, G1.w, yc1.w, yp1.w);

        if (hs) {  // uniform: only blocks whose EXT tile contains the source
          val0.x = fmaf(sm0.x, xt, val0.x);
          val0.y = fmaf(sm0.y, xt, val0.y);
          val0.z = fmaf(sm0.z, xt, val0.z);
          val0.w = fmaf(sm0.w, xt, val0.w);
          val1.x = fmaf(sm1.x, xt, val1.x);
          val1.y = fmaf(sm1.y, xt, val1.y);
          val1.z = fmaf(sm1.z, xt, val1.z);
          val1.w = fmaf(sm1.w, xt, val1.w);
        }

        yp0 = yc0; yp1 = yc1;
        yc0 = val0; yc1 = val1;

        if (j < KSTEP - 1) {           // final step's LDS state never read
          *(float4*)&pong[lo] = val0;  // lg==7 writes 0 into right pad
          *(float4*)&pong[lo + 4] = val1;
        }

        pv0 = val0; pv1 = val1;
      }
      pop = op;

      if (j < KSTEP - 1) {
        // lgkm-only barrier: LDS ping/pong visibility without vmcnt drain.
        asm volatile("s_waitcnt lgkmcnt(0)\n\ts_barrier" ::: "memory");
      }
      float* tmp = ping; ping = pong; pong = tmp;
    }

    // Final step's output store (device-coherent).
    if (til) {
      store_f4_dc(pop + gofs, pv0);
      store_f4_dc(pop + gofs + 4, pv1);
    }

    if (p + 1 < p1) {
      // ---- Release: __syncthreads drains every thread's vmcnt, so all the
      // block's sc0sc1 stores are at LLC; then a RELAXED agent flag store.
      __syncthreads();
      if (tid == 0)
        __hip_atomic_store(&flags[bid], (unsigned)(p + 1), __ATOMIC_RELAXED,
                           __HIP_MEMORY_SCOPE_AGENT);
    }
  }
#undef CELL
}

extern "C" void kernel_launch(void* const* d_in, const int* in_sizes, int n_in,
                              void* d_out, int out_size, void* d_ws,
                              size_t ws_size, hipStream_t stream) {
  const float* x = (const float*)d_in[0];  // [B, T, 1]
  const float* c = (const float*)d_in[1];  // [192,192]
  const float* b = (const float*)d_in[2];  // [192,192]
  float* out = (float*)d_out;              // [B, T, 192, 192]
  unsigned int* flags = (unsigned int*)d_ws;

  // Zero the 256 per-block phase flags (stream-ordered; graph-capturable).
  hipMemsetAsync(flags, 0, 256 * sizeof(unsigned int), stream);

  dim3 grid(NXg / TS, NYg / TS, BATCH);  // 8 x 8 x 4 = 256 blocks = 1/CU
  int p0 = 0, p1 = NPHASE;
  const float* ca = c; const float* ba = b; const float* xa = x; float* oa = out;
  unsigned int* fa = flags;
  void* args[] = {(void*)&ca, (void*)&ba, (void*)&xa, (void*)&oa,
                  (void*)&fa, (void*)&p0, (void*)&p1};
  hipError_t err = hipLaunchCooperativeKernel(
      (const void*)wave_kernel, grid, dim3(NTHREADS), args, 0, stream);
  if (err != hipSuccess) {
    // Fallback: classic 16-launch path (handshake never fires when a launch
    // covers a single phase; visibility via kernel boundaries).
    for (int p = 0; p < NPHASE; ++p) {
      wave_kernel<<<grid, NTHREADS, 0, stream>>>(c, b, x, out, flags, p, p + 1);
    }
  }
}

// Round 8
// 396.806 us; speedup vs baseline: 1.1282x; 1.1282x over previous
//
#include <hip/hip_runtime.h>

// WaveCell round-14: ISOLATION EXPERIMENT — the round-13 two-step math
// (2 time steps per barrier via register-retained off-row intermediates)
// on the PROVEN round-8 infrastructure (16 classic launches, plain float4
// stores, kernel-boundary coherence; no coop / flags / atomics / sc0sc1).
// r13 failed (absmax 1e11) but the math re-audit found no error; this run
// decides {math bug} vs {fence-free-infra bug}. Also learned r9-r12: the
// cooperative path carries ~135us fixed harness overhead -> abandoned; the
// classic launch boundary is only ~2us.
// Super-step: read y(T) rows r+-1, r+-2 from LDS (8x b128); compute step A
// = y(T+1) for rows r-1, r, r+1 in registers (prev y(T-1) of those rows
// retained from the previous super-step); compute step B = y(T+2) for row r
// (prev = y(T) = own yc); ONE ds_write pair + ONE lgkm barrier per 2 steps.

#define NXg 192
#define NYg 192
#define BATCH 4
#define TSTEPS 256
#define CELLS (NXg * NYg)

#define TS 24
#define KSTEP 16
#define EXT 56                   // TS + 2*KSTEP
#define LROWS 60                 // 2 guard rows top + 56 data + 2 guard bottom
#define LPITCH 68                // dwords/row: 4 pad | 56 data | 8 pad
#define LSZ (LROWS * LPITCH)
#define NTHREADS 448             // 56 rows x 8 lanes (lane 7 = zero lane)

#define SRC_X 96
#define SRC_Y 32

__device__ __forceinline__ void mkcoef(float4 cv, float4 bv, float inv_h2,
                                       float4& D, float4& E, float4& Gq) {
  float ai;
  ai = 1.0f / (1.0e6f + 500.0f * bv.x);
  D.x = 2.0e6f * ai; E.x = (1.0e6f - 500.0f * bv.x) * ai; Gq.x = cv.x * cv.x * inv_h2 * ai;
  ai = 1.0f / (1.0e6f + 500.0f * bv.y);
  D.y = 2.0e6f * ai; E.y = (1.0e6f - 500.0f * bv.y) * ai; Gq.y = cv.y * cv.y * inv_h2 * ai;
  ai = 1.0f / (1.0e6f + 500.0f * bv.z);
  D.z = 2.0e6f * ai; E.z = (1.0e6f - 500.0f * bv.z) * ai; Gq.z = cv.z * cv.z * inv_h2 * ai;
  ai = 1.0f / (1.0e6f + 500.0f * bv.w);
  D.w = 2.0e6f * ai; E.w = (1.0e6f - 500.0f * bv.w) * ai; Gq.w = cv.w * cv.w * inv_h2 * ai;
}

// val = D*y - E*p + G*(up+dn+lf+rt-4y)
#define CELL(dst, up_, dn_, lf_, rt_, D_, E_, G_, y_, p_)             \
  {                                                                   \
    float s_ = fmaf(-4.0f, y_, (up_ + dn_) + (lf_ + rt_));            \
    dst = fmaf(G_, s_, fmaf(-E_, p_, D_ * y_));                       \
  }

// 8 columns of one row: center (cA,cB), up (uA,uB), down (dA,dB).
#define ROW8(vA, vB, uA, uB, dA, dB, cA, cB, lq, rq, Da, Db, Ea, Eb, Ga, Gb, pA, pB) \
  CELL(vA.x, uA.x, dA.x, lq,   cA.y, Da.x, Ea.x, Ga.x, cA.x, pA.x);   \
  CELL(vA.y, uA.y, dA.y, cA.x, cA.z, Da.y, Ea.y, Ga.y, cA.y, pA.y);   \
  CELL(vA.z, uA.z, dA.z, cA.y, cA.w, Da.z, Ea.z, Ga.z, cA.z, pA.z);   \
  CELL(vA.w, uA.w, dA.w, cA.z, cB.x, Da.w, Ea.w, Ga.w, cA.w, pA.w);   \
  CELL(vB.x, uB.x, dB.x, cA.w, cB.y, Db.x, Eb.x, Gb.x, cB.x, pB.x);   \
  CELL(vB.y, uB.y, dB.y, cB.x, cB.z, Db.y, Eb.y, Gb.y, cB.y, pB.y);   \
  CELL(vB.z, uB.z, dB.z, cB.y, cB.w, Db.z, Eb.z, Gb.z, cB.z, pB.z);   \
  CELL(vB.w, uB.w, dB.w, cB.z, rq,   Db.w, Eb.w, Gb.w, cB.w, pB.w);

#define ADDSRC(vA, vB, sA, sB, xt_)                                   \
  vA.x = fmaf(sA.x, xt_, vA.x); vA.y = fmaf(sA.y, xt_, vA.y);         \
  vA.z = fmaf(sA.z, xt_, vA.z); vA.w = fmaf(sA.w, xt_, vA.w);         \
  vB.x = fmaf(sB.x, xt_, vB.x); vB.y = fmaf(sB.y, xt_, vB.y);         \
  vB.z = fmaf(sB.z, xt_, vB.z); vB.w = fmaf(sB.w, xt_, vB.w);

__global__ __launch_bounds__(NTHREADS) void wave_kernel(
    const float* __restrict__ cgp, const float* __restrict__ bgp,
    const float* __restrict__ x, float* __restrict__ out, int t0) {
  __shared__ float buf0[LSZ];
  __shared__ float buf1[LSZ];

  const int tid = threadIdx.x;
  const int lr = tid >> 3;      // local row 0..55
  const int lg = tid & 7;       // 8-wide col group; lg==7 is the zero lane
  const int bcol = blockIdx.x;
  const int brow = blockIdx.y;
  const int bb = blockIdx.z;
  const int r0 = brow * TS - KSTEP;
  const int c0 = bcol * TS - KSTEP;
  const int obase = bb * TSTEPS * CELLS;
  const float inv_h2 = (float)(1.0 / (2.0 * 1.01 * 1.01 * 1.0e-3 * 1.0e-3));

  const int gr = r0 + lr;
  const int gc = c0 + 8 * lg;   // multiple of 8; never straddles domain edge
  const bool colOK = (lg < 7) && (gc >= 0) && (gc < NYg);
  const bool idC = colOK && (gr >= 0) && (gr < NXg);
  const bool idU = colOK && (gr - 1 >= 0) && (gr - 1 < NXg);
  const bool idD = colOK && (gr + 1 >= 0) && (gr + 1 < NXg);
  const bool til = (lr >= KSTEP) && (lr < KSTEP + TS) && (lg >= 2) && (lg < 5);
  const bool hs = (SRC_X >= r0 - 1) && (SRC_X <= r0 + EXT) &&
                  (SRC_Y >= c0) && (SRC_Y < c0 + EXT);
  const int ofsC = idC ? (gr * NYg + gc) : 0;
  const int ofsU = idU ? ((gr - 1) * NYg + gc) : 0;
  const int ofsD = idD ? ((gr + 1) * NYg + gc) : 0;

  const float4 z4 = make_float4(0.f, 0.f, 0.f, 0.f);

  // ---- Coefficients for rows r-1, r, r+1 (overlaps load latency). ----
  float4 Dc0 = z4, Dc1 = z4, Ey0 = z4, Ey1 = z4, G0 = z4, G1 = z4;   // row r
  float4 DU0 = z4, DU1 = z4, EU0 = z4, EU1 = z4, GU0 = z4, GU1 = z4; // row r-1
  float4 DD0 = z4, DD1 = z4, ED0 = z4, ED1 = z4, GD0 = z4, GD1 = z4; // row r+1
  if (idC) {
    mkcoef(*(const float4*)(cgp + ofsC), *(const float4*)(bgp + ofsC), inv_h2, Dc0, Ey0, G0);
    mkcoef(*(const float4*)(cgp + ofsC + 4), *(const float4*)(bgp + ofsC + 4), inv_h2, Dc1, Ey1, G1);
  }
  if (idU) {
    mkcoef(*(const float4*)(cgp + ofsU), *(const float4*)(bgp + ofsU), inv_h2, DU0, EU0, GU0);
    mkcoef(*(const float4*)(cgp + ofsU + 4), *(const float4*)(bgp + ofsU + 4), inv_h2, DU1, EU1, GU1);
  }
  if (idD) {
    mkcoef(*(const float4*)(cgp + ofsD), *(const float4*)(bgp + ofsD), inv_h2, DD0, ED0, GD0);
    mkcoef(*(const float4*)(cgp + ofsD + 4), *(const float4*)(bgp + ofsD + 4), inv_h2, DD1, ED1, GD1);
  }

  // Source column mask x per-row row-hit scalars.
  float4 smc0 = z4, smc1 = z4;
  if (colOK) {
    smc0.x = (gc + 0 == SRC_Y) ? 1.0f : 0.0f;
    smc0.y = (gc + 1 == SRC_Y) ? 1.0f : 0.0f;
    smc0.z = (gc + 2 == SRC_Y) ? 1.0f : 0.0f;
    smc0.w = (gc + 3 == SRC_Y) ? 1.0f : 0.0f;
    smc1.x = (gc + 4 == SRC_Y) ? 1.0f : 0.0f;
    smc1.y = (gc + 5 == SRC_Y) ? 1.0f : 0.0f;
    smc1.z = (gc + 6 == SRC_Y) ? 1.0f : 0.0f;
    smc1.w = (gc + 7 == SRC_Y) ? 1.0f : 0.0f;
  }
  const float fU = (gr - 1 == SRC_X) ? 1.0f : 0.0f;
  const float fC = (gr == SRC_X) ? 1.0f : 0.0f;
  const float fD = (gr + 1 == SRC_X) ? 1.0f : 0.0f;
  float4 smU0, smU1, smC0, smC1, smD0, smD1;
  smU0.x = smc0.x * fU; smU0.y = smc0.y * fU; smU0.z = smc0.z * fU; smU0.w = smc0.w * fU;
  smU1.x = smc1.x * fU; smU1.y = smc1.y * fU; smU1.z = smc1.z * fU; smU1.w = smc1.w * fU;
  smC0.x = smc0.x * fC; smC0.y = smc0.y * fC; smC0.z = smc0.z * fC; smC0.w = smc0.w * fC;
  smC1.x = smc1.x * fC; smC1.y = smc1.y * fC; smC1.z = smc1.z * fC; smC1.w = smc1.w * fC;
  smD0.x = smc0.x * fD; smD0.y = smc0.y * fD; smD0.z = smc0.z * fD; smD0.w = smc0.w * fD;
  smD1.x = smc1.x * fD; smD1.y = smc1.y * fD; smD1.z = smc1.z * fD; smD1.w = smc1.w * fD;

  // ---- State reload: y(t0-1) own row; y(t0-2) rows r-1, r, r+1. ----
  float4 yc0 = z4, yc1 = z4;
  float4 ypc0 = z4, ypc1 = z4, ypu0 = z4, ypu1 = z4, ypd0 = z4, ypd1 = z4;
  if (t0 > 0) {
    const float* o1 = out + obase + (t0 - 1) * CELLS;
    const float* o2 = out + obase + (t0 - 2) * CELLS;
    if (idC) {
      yc0 = *(const float4*)(o1 + ofsC);
      yc1 = *(const float4*)(o1 + ofsC + 4);
      ypc0 = *(const float4*)(o2 + ofsC);
      ypc1 = *(const float4*)(o2 + ofsC + 4);
    }
    if (idU) {
      ypu0 = *(const float4*)(o2 + ofsU);
      ypu1 = *(const float4*)(o2 + ofsU + 4);
    }
    if (idD) {
      ypd0 = *(const float4*)(o2 + ofsD);
      ypd1 = *(const float4*)(o2 + ofsD + 4);
    }
  }
  float xs[KSTEP];
  {
    const float4* xp = (const float4*)(x + bb * TSTEPS + t0);
    float4 a0 = xp[0], a1 = xp[1], a2 = xp[2], a3 = xp[3];
    xs[0] = a0.x; xs[1] = a0.y; xs[2] = a0.z; xs[3] = a0.w;
    xs[4] = a1.x; xs[5] = a1.y; xs[6] = a1.z; xs[7] = a1.w;
    xs[8] = a2.x; xs[9] = a2.y; xs[10] = a2.z; xs[11] = a2.w;
    xs[12] = a3.x; xs[13] = a3.y; xs[14] = a3.z; xs[15] = a3.w;
  }

  // LDS address (data row lr maps to LDS row lr+2; 2 guard rows each side).
  const int lo = (lr + 2) * LPITCH + 4 + 8 * lg;

  // Zero the 4 guard rows (0,1,58,59) of both buffers; never written again
  // (publishes cover LDS rows 2..57 only).
  if (tid < 136) {
    float* bufp = (tid < 68) ? buf0 : buf1;
    const int q2 = tid % 68;
    const int grow = q2 / 17;
    const int row = (grow < 2) ? grow : (56 + grow);
    *(float4*)&bufp[row * LPITCH + 4 * (q2 % 17)] = z4;
  }

  // Scatter y(t0-1) into buf0 data rows.
  *(float4*)&buf0[lo] = yc0;
  *(float4*)&buf0[lo + 4] = yc1;
  asm volatile("s_waitcnt lgkmcnt(0)\n\ts_barrier" ::: "memory");

  float* ping = buf0;
  float* pong = buf1;

  // ---- 8 super-steps x 2 time steps (fully unrolled; xs[] reg-indexed). ----
#pragma unroll
  for (int k = 0; k < KSTEP / 2; ++k) {
    const float xtA = xs[2 * k];
    const float xtB = xs[2 * k + 1];

    // Read y(T) rows r-2, r-1, r+1, r+2 (own row is in yc registers).
    float4 u20 = *(float4*)&ping[lo - 2 * LPITCH];
    float4 u21 = *(float4*)&ping[lo - 2 * LPITCH + 4];
    float4 u10 = *(float4*)&ping[lo - LPITCH];
    float4 u11 = *(float4*)&ping[lo - LPITCH + 4];
    float4 d10 = *(float4*)&ping[lo + LPITCH];
    float4 d11 = *(float4*)&ping[lo + LPITCH + 4];
    float4 d20 = *(float4*)&ping[lo + 2 * LPITCH];
    float4 d21 = *(float4*)&ping[lo + 2 * LPITCH + 4];

    // Left/right column neighbors for the three step-A rows.
    float lqU = __shfl_up(u11.w, 1);   lqU = (lg == 0) ? 0.0f : lqU;
    float rqU = __shfl_down(u10.x, 1); rqU = (lg == 7) ? 0.0f : rqU;
    float lqC = __shfl_up(yc1.w, 1);   lqC = (lg == 0) ? 0.0f : lqC;
    float rqC = __shfl_down(yc0.x, 1); rqC = (lg == 7) ? 0.0f : rqC;
    float lqD = __shfl_up(d11.w, 1);   lqD = (lg == 0) ? 0.0f : lqD;
    float rqD = __shfl_down(d10.x, 1); rqD = (lg == 7) ? 0.0f : rqD;

    // Step A: y(T+1) for rows r-1, r, r+1 (registers only).
    float4 vU0, vU1, vC0, vC1, vD0, vD1;
    ROW8(vU0, vU1, u20, u21, yc0, yc1, u10, u11, lqU, rqU,
         DU0, DU1, EU0, EU1, GU0, GU1, ypu0, ypu1);
    ROW8(vC0, vC1, u10, u11, d10, d11, yc0, yc1, lqC, rqC,
         Dc0, Dc1, Ey0, Ey1, G0, G1, ypc0, ypc1);
    ROW8(vD0, vD1, yc0, yc1, d20, d21, d10, d11, lqD, rqD,
         DD0, DD1, ED0, ED1, GD0, GD1, ypd0, ypd1);
    if (hs) {
      ADDSRC(vU0, vU1, smU0, smU1, xtA);
      ADDSRC(vC0, vC1, smC0, smC1, xtA);
      ADDSRC(vD0, vD1, smD0, smD1, xtA);
    }

    // Step B: y(T+2) for row r (prev = y(T) = yc).
    float lqB = __shfl_up(vC1.w, 1);   lqB = (lg == 0) ? 0.0f : lqB;
    float rqB = __shfl_down(vC0.x, 1); rqB = (lg == 7) ? 0.0f : rqB;
    float4 w0, w1;
    ROW8(w0, w1, vU0, vU1, vD0, vD1, vC0, vC1, lqB, rqB,
         Dc0, Dc1, Ey0, Ey1, G0, G1, yc0, yc1);
    if (hs) {
      ADDSRC(w0, w1, smC0, smC1, xtB);
    }

    // Output stores (plain; retire by kernel end / next-launch boundary).
    if (til) {
      float* opA = out + obase + (t0 + 2 * k) * CELLS;
      *(float4*)(opA + ofsC) = vC0;
      *(float4*)(opA + ofsC + 4) = vC1;
      float* opB = opA + CELLS;
      *(float4*)(opB + ofsC) = w0;
      *(float4*)(opB + ofsC + 4) = w1;
    }

    // Publish y(T+2); rotate retained registers.
    if (k < KSTEP / 2 - 1) {
      *(float4*)&pong[lo] = w0;
      *(float4*)&pong[lo + 4] = w1;
    }
    ypu0 = vU0; ypu1 = vU1;
    ypc0 = vC0; ypc1 = vC1;
    ypd0 = vD0; ypd1 = vD1;
    yc0 = w0; yc1 = w1;

    if (k < KSTEP / 2 - 1) {
      // lgkm-only barrier: LDS ping/pong visibility without vmcnt drain.
      asm volatile("s_waitcnt lgkmcnt(0)\n\ts_barrier" ::: "memory");
    }
    float* tmp = ping; ping = pong; pong = tmp;
  }
}

extern "C" void kernel_launch(void* const* d_in, const int* in_sizes, int n_in,
                              void* d_out, int out_size, void* d_ws,
                              size_t ws_size, hipStream_t stream) {
  const float* x = (const float*)d_in[0];  // [B, T, 1]
  const float* c = (const float*)d_in[1];  // [192,192]
  const float* b = (const float*)d_in[2];  // [192,192]
  float* out = (float*)d_out;              // [B, T, 192, 192]

  dim3 grid(NXg / TS, NYg / TS, BATCH);    // 8 x 8 x 4 = 256 blocks
  for (int t0 = 0; t0 < TSTEPS; t0 += KSTEP) {
    wave_kernel<<<grid, NTHREADS, 0, stream>>>(c, b, x, out, t0);
  }
}